// Round 14
// baseline (339.803 us; speedup 1.0000x reference)
//
#include <hip/hip_runtime.h>
#include <hip/hip_bf16.h>
#include <math.h>

#define E_EXPERTS 8
#define D_DIM 768
#define H_DIM 3072
#define N_TOK 8192          // B*T = 4*2048
#define SLOTS (2 * N_TOK)
#define SCAT_BLOCKS 32      // hist/scatter blocks (256 tokens each)

typedef unsigned short ushort_t;
typedef __attribute__((ext_vector_type(8))) __bf16 bf16x8;
typedef __attribute__((ext_vector_type(4))) float f32x4;

__device__ __forceinline__ unsigned short f2bf(float f) {
    unsigned int u = __float_as_uint(f);
    unsigned int r = (u + 0x7FFFu + ((u >> 16) & 1u)) >> 16;
    return (unsigned short)r;
}

// async 16B global -> LDS (wave-uniform LDS base + lane*16; global addr per-lane)
__device__ __forceinline__ void gload_lds16(const void* g, void* l) {
    __builtin_amdgcn_global_load_lds(
        (const __attribute__((address_space(1))) unsigned int*)g,
        (__attribute__((address_space(3))) unsigned int*)l, 16, 0, 0);
}

// ---------------- prep kernels ----------------

// dst[e][c][r] = bf16(src[e][r][c]);  R,C multiples of 64
__global__ void transpose_conv_kernel(const float* __restrict__ src, ushort_t* __restrict__ dst,
                                      int R, int C) {
    __shared__ float tile[64][65];
    int e = blockIdx.z;
    const float* S = src + (size_t)e * R * C;
    ushort_t* Dp = dst + (size_t)e * R * C;
    int c0 = blockIdx.x * 64, r0 = blockIdx.y * 64;
    int tx = threadIdx.x & 15, ty = threadIdx.x >> 4;  // 16 x 16
#pragma unroll
    for (int p = 0; p < 4; p++) {
        float4 v = *(const float4*)&S[(size_t)(r0 + ty + 16 * p) * C + c0 + tx * 4];
        tile[ty + 16 * p][tx * 4 + 0] = v.x;
        tile[ty + 16 * p][tx * 4 + 1] = v.y;
        tile[ty + 16 * p][tx * 4 + 2] = v.z;
        tile[ty + 16 * p][tx * 4 + 3] = v.w;
    }
    __syncthreads();
#pragma unroll
    for (int p = 0; p < 4; p++) {
        int cc = ty + 16 * p;
        int rr = tx * 4;
        ushort4 o;
        o.x = f2bf(tile[rr + 0][cc]);
        o.y = f2bf(tile[rr + 1][cc]);
        o.z = f2bf(tile[rr + 2][cc]);
        o.w = f2bf(tile[rr + 3][cc]);
        *(ushort4*)&Dp[(size_t)(c0 + cc) * R + r0 + rr] = o;
    }
}

// ---------------- routing ----------------

__global__ void gate_kernel(const float* __restrict__ x, const float* __restrict__ Wg,
                            const float* __restrict__ bg, ushort_t* __restrict__ xb,
                            int* __restrict__ top_idx, float* __restrict__ top_w) {
    int w = threadIdx.x >> 6, lane = threadIdx.x & 63;
    int t = blockIdx.x * 4 + w;
    if (t >= N_TOK) return;
    const float* xr = x + (size_t)t * D_DIM;
    float xs[12];
#pragma unroll
    for (int j = 0; j < 12; j++) xs[j] = xr[lane + 64 * j];
#pragma unroll
    for (int j = 0; j < 12; j++) xb[(size_t)t * D_DIM + lane + 64 * j] = f2bf(xs[j]);
    float pr[8];
#pragma unroll
    for (int ee = 0; ee < 8; ee++) {
        const float* wr = Wg + ee * D_DIM;
        float p = 0.f;
#pragma unroll
        for (int j = 0; j < 12; j++) p += xs[j] * wr[lane + 64 * j];
#pragma unroll
        for (int o = 32; o > 0; o >>= 1) p += __shfl_xor(p, o);
        pr[ee] = p + bg[ee];
    }
    float mx = pr[0];
#pragma unroll
    for (int ee = 1; ee < 8; ee++) mx = fmaxf(mx, pr[ee]);
    float s = 0.f;
#pragma unroll
    for (int ee = 0; ee < 8; ee++) { pr[ee] = expf(pr[ee] - mx); s += pr[ee]; }
    float inv = 1.f / s;
#pragma unroll
    for (int ee = 0; ee < 8; ee++) pr[ee] *= inv;
    int i0 = 0;
#pragma unroll
    for (int ee = 1; ee < 8; ee++) if (pr[ee] > pr[i0]) i0 = ee;
    int i1 = -1;
#pragma unroll
    for (int ee = 0; ee < 8; ee++) {
        if (ee == i0) continue;
        if (i1 < 0 || pr[ee] > pr[i1]) i1 = ee;
    }
    if (lane == 0) {
        top_idx[2 * t] = i0;
        top_idx[2 * t + 1] = i1;
        top_w[2 * t] = pr[i0];
        top_w[2 * t + 1] = pr[i1];
    }
}

__global__ void hist_kernel(const int* __restrict__ top_idx, int* __restrict__ bc) {
    __shared__ int h[E_EXPERTS];
    if (threadIdx.x < E_EXPERTS) h[threadIdx.x] = 0;
    __syncthreads();
    int t = blockIdx.x * 256 + threadIdx.x;
    atomicAdd(&h[top_idx[2 * t]], 1);
    atomicAdd(&h[top_idx[2 * t + 1]], 1);
    __syncthreads();
    if (threadIdx.x < E_EXPERTS) bc[blockIdx.x * E_EXPERTS + threadIdx.x] = h[threadIdx.x];
}

__global__ void scan_kernel(const int* __restrict__ bc, int* __restrict__ counts,
                            int* __restrict__ offsets, int* __restrict__ base) {
    int tid = threadIdx.x;
    if (tid < E_EXPERTS) {
        int acc = 0;
        for (int b = 0; b < SCAT_BLOCKS; b++) {
            base[b * E_EXPERTS + tid] = acc;
            acc += bc[b * E_EXPERTS + tid];
        }
        counts[tid] = acc;
    }
    __syncthreads();
    if (tid == 0) {
        int acc = 0;
        for (int e = 0; e < E_EXPERTS; e++) { offsets[e] = acc; acc += counts[e]; }
    }
    __syncthreads();
    if (tid < E_EXPERTS) {
        int o = offsets[tid];
        for (int b = 0; b < SCAT_BLOCKS; b++) base[b * E_EXPERTS + tid] += o;
    }
}

__global__ void scatter_kernel(const int* __restrict__ top_idx, const float* __restrict__ top_w,
                               const int* __restrict__ base, int* __restrict__ perm,
                               float* __restrict__ wgt) {
    __shared__ int cur[E_EXPERTS];
    if (threadIdx.x < E_EXPERTS) cur[threadIdx.x] = 0;
    __syncthreads();
    int t = blockIdx.x * 256 + threadIdx.x;
#pragma unroll
    for (int sl = 0; sl < 2; sl++) {
        int ee = top_idx[2 * t + sl];
        int p = atomicAdd(&cur[ee], 1);
        int s = base[blockIdx.x * E_EXPERTS + ee] + p;
        perm[s] = t;
        wgt[s] = top_w[2 * t + sl];
    }
}

// ------- GEMM1: 256x128 tile, 512 threads (8 waves 4Mx2N, per-wave 64x64), BK=64 -------
// Single-buffer 48 KiB LDS, __launch_bounds__(512,2). K-tile split into kk halves
// (VGPR 64, no spill). Per K-tile: sync; {8 reads, 16 MFMA} x2; sync; stage t+1.
// Swizzle (r6/r10-verified): source granule (tid&7)^(row&7), LDS dest linear; reads XOR
// granule with (lr&7) -> conflicts 0, staging instructions cover full 128B lines.
// Grid 1-D XCD-grouped: wgid = c + 8*(mb + 10*q); g = q*8+c -> (e = g/24, nb = g%24).
__global__ __launch_bounds__(512, 2) void moe_gemm1_kernel(
    const ushort_t* __restrict__ A, const ushort_t* __restrict__ BT,
    const float* __restrict__ bias, const int* __restrict__ offsets,
    const int* __restrict__ counts, const int* __restrict__ perm,
    ushort_t* __restrict__ Hout) {
    constexpr int K = D_DIM;
    constexpr int KT = K / 64;
    constexpr int NB = H_DIM / 128;   // 24
    constexpr int MBL = 10;           // covers ne <= 2560

    const int wgid = blockIdx.x;
    const int c = wgid & 7;
    const int r = wgid >> 3;
    const int mb = r % MBL;
    const int q = r / MBL;
    const int g = q * 8 + c;
    const int e = g / NB;
    const int nb = g % NB;

    const int ne = counts[e];
    const int m0 = mb * 256;
    if (m0 >= ne) return;
    const int n0 = nb * 128;
    const int base = offsets[e];
    const ushort_t* Bt = BT + (size_t)e * ((size_t)H_DIM * K);

    __shared__ alignas(16) ushort_t As[256 * 64];   // 32 KB
    __shared__ alignas(16) ushort_t Bs[128 * 64];   // 16 KB

    const int tid = threadIdx.x;
    const int lane = tid & 63;
    const int w = tid >> 6;
    const int wm = w >> 1, wn = w & 1;           // 4 x 2 wave grid
    const int lr = lane & 15;
    const int lk8 = lane >> 4;                   // base k-granule 0..3

    const int trow = tid >> 3;                   // 0..63
    const int sg8 = (((tid & 7) ^ (trow & 7)) * 8);
    int a_off[4], b_off[2];
#pragma unroll
    for (int i = 0; i < 4; i++) {
        int row = i * 64 + trow;
        int rcl = min(m0 + row, ne - 1);
        a_off[i] = perm[base + rcl] * K + sg8;
    }
#pragma unroll
    for (int i = 0; i < 2; i++)
        b_off[i] = (n0 + i * 64 + trow) * K + sg8;

    auto stage = [&](int tt) {
#pragma unroll
        for (int i = 0; i < 4; i++)
            gload_lds16(A + (size_t)a_off[i] + (size_t)tt * 64, &As[(i * 512 + w * 64) * 8]);
#pragma unroll
        for (int i = 0; i < 2; i++)
            gload_lds16(Bt + (size_t)b_off[i] + (size_t)tt * 64, &Bs[(i * 512 + w * 64) * 8]);
    };

    f32x4 acc[4][4];
#pragma unroll
    for (int i = 0; i < 4; i++)
#pragma unroll
        for (int j = 0; j < 4; j++) acc[i][j] = (f32x4){0.f, 0.f, 0.f, 0.f};

    const int cg0 = ((0 * 4 + lk8) ^ (lr & 7)) << 3;
    const int cg1 = ((1 * 4 + lk8) ^ (lr & 7)) << 3;

    stage(0);
    for (int t = 0; t < KT; ++t) {
        __syncthreads();                         // vm-drain: tile t visible in LDS
        {
            bf16x8 bfr[4], afr[4];
#pragma unroll
            for (int f = 0; f < 4; f++)
                bfr[f] = *(const bf16x8*)&Bs[(wn * 64 + f * 16 + lr) * 64 + cg0];
#pragma unroll
            for (int f = 0; f < 4; f++)
                afr[f] = *(const bf16x8*)&As[(wm * 64 + f * 16 + lr) * 64 + cg0];
#pragma unroll
            for (int fm = 0; fm < 4; fm++)
#pragma unroll
                for (int fc = 0; fc < 4; fc++)
                    acc[fm][fc] = __builtin_amdgcn_mfma_f32_16x16x32_bf16(afr[fm], bfr[fc], acc[fm][fc], 0, 0, 0);
        }
        {
            bf16x8 bfr[4], afr[4];
#pragma unroll
            for (int f = 0; f < 4; f++)
                bfr[f] = *(const bf16x8*)&Bs[(wn * 64 + f * 16 + lr) * 64 + cg1];
#pragma unroll
            for (int f = 0; f < 4; f++)
                afr[f] = *(const bf16x8*)&As[(wm * 64 + f * 16 + lr) * 64 + cg1];
#pragma unroll
            for (int fm = 0; fm < 4; fm++)
#pragma unroll
                for (int fc = 0; fc < 4; fc++)
                    acc[fm][fc] = __builtin_amdgcn_mfma_f32_16x16x32_bf16(afr[fm], bfr[fc], acc[fm][fc], 0, 0, 0);
        }
        __syncthreads();                         // all waves done reading tile t
        if (t + 1 < KT) stage(t + 1);
    }

    const int rg0 = lk8 * 4;
#pragma unroll
    for (int fr = 0; fr < 4; fr++) {
#pragma unroll
        for (int fc = 0; fc < 4; fc++) {
            int cn = n0 + wn * 64 + fc * 16 + lr;
            float bi = bias[e * H_DIM + cn];
            f32x4 v = acc[fr][fc];
#pragma unroll
            for (int rg = 0; rg < 4; rg++) {
                int rm = m0 + wm * 64 + fr * 16 + rg0 + rg;
                if (rm < ne) {
                    float xv = v[rg] + bi;
                    // gelu(x) ~= x * sigmoid(2*0.7978845608*(x + 0.044715 x^3))
                    float u = xv * 1.5957691216f * __builtin_fmaf(0.044715f * xv, xv, 1.0f);
                    float gl = xv / (1.f + __expf(-u));
                    Hout[(size_t)(base + rm) * H_DIM + cn] = f2bf(gl);
                }
            }
        }
    }
}

// ------- GEMM2: 128x128, BK=64, 256 threads, single-buffer, (256,4); FUSED combine -------
// Per K-tile: sync; reads; sync; stage t+1 (async, overlaps MFMA); MFMA.
// A = Hb contiguous slots, B = W2T[e]; epilogue: unsafeAtomicAdd(out[tok], w*(acc+bias))
// -- exactly 2 fp32 atomics per output element; replaces the y buffer + combine pass.
__global__ __launch_bounds__(256, 4) void moe_gemm2_kernel(
    const ushort_t* __restrict__ A, const ushort_t* __restrict__ BT,
    const float* __restrict__ bias, const int* __restrict__ offsets,
    const int* __restrict__ counts, const int* __restrict__ perm,
    const float* __restrict__ wgt, float* __restrict__ Out) {
    constexpr int K = H_DIM;
    constexpr int KT = K / 64;
    constexpr int NB = D_DIM / 128;   // 6
    constexpr int MBL = 20;           // covers ne <= 2560

    const int wgid = blockIdx.x;
    const int c = wgid & 7;
    const int r = wgid >> 3;
    const int mb = r % MBL;
    const int q = r / MBL;
    const int g = q * 8 + c;
    const int e = g / NB;
    const int nb = g % NB;

    const int ne = counts[e];
    const int m0 = mb * 128;
    if (m0 >= ne) return;
    const int n0 = nb * 128;
    const int base = offsets[e];
    const ushort_t* Bt = BT + (size_t)e * ((size_t)D_DIM * K);

    __shared__ alignas(16) ushort_t As[128 * 64];   // 16 KB
    __shared__ alignas(16) ushort_t Bs[128 * 64];   // 16 KB

    const int tid = threadIdx.x;
    const int lane = tid & 63;
    const int w = tid >> 6;
    const int wm = w >> 1, wn = w & 1;           // 2 x 2 wave grid
    const int lr = lane & 15;
    const int lk8 = lane >> 4;

    const int trow = tid >> 3;                   // 0..31
    const int sg8 = (((tid & 7) ^ (trow & 7)) * 8);
    int a_off[4], b_off[4];
#pragma unroll
    for (int i = 0; i < 4; i++) {
        int row = i * 32 + trow;
        int rcl = min(m0 + row, ne - 1);
        a_off[i] = (base + rcl) * K + sg8;
        b_off[i] = (n0 + row) * K + sg8;
    }

    auto stage = [&](int tt) {
#pragma unroll
        for (int i = 0; i < 4; i++)
            gload_lds16(A + (size_t)a_off[i] + (size_t)tt * 64, &As[(i * 256 + w * 64) * 8]);
#pragma unroll
        for (int i = 0; i < 4; i++)
            gload_lds16(Bt + (size_t)b_off[i] + (size_t)tt * 64, &Bs[(i * 256 + w * 64) * 8]);
    };

    f32x4 acc[4][4];
#pragma unroll
    for (int i = 0; i < 4; i++)
#pragma unroll
        for (int j = 0; j < 4; j++) acc[i][j] = (f32x4){0.f, 0.f, 0.f, 0.f};

    const int cg0 = ((0 * 4 + lk8) ^ (lr & 7)) << 3;
    const int cg1 = ((1 * 4 + lk8) ^ (lr & 7)) << 3;

    stage(0);
    for (int t = 0; t < KT; ++t) {
        __syncthreads();                         // vm-drain: tile t visible in LDS
        bf16x8 bfr[4][2], afr[4][2];
#pragma unroll
        for (int fc = 0; fc < 4; fc++) {
            int Rb = (wn * 64 + fc * 16 + lr) * 64;
            bfr[fc][0] = *(const bf16x8*)&Bs[Rb + cg0];
            bfr[fc][1] = *(const bf16x8*)&Bs[Rb + cg1];
        }
#pragma unroll
        for (int pl = 0; pl < 4; pl++) {
            int Ra = (wm * 64 + pl * 16 + lr) * 64;
            afr[pl][0] = *(const bf16x8*)&As[Ra + cg0];
            afr[pl][1] = *(const bf16x8*)&As[Ra + cg1];
        }
        __syncthreads();                         // lgkm-drain: reads in regs, buffer free
        if (t + 1 < KT) stage(t + 1);            // async loads overlap the MFMA below
#pragma unroll
        for (int pl = 0; pl < 4; pl++)
#pragma unroll
            for (int fc = 0; fc < 4; fc++) {
                acc[pl][fc] = __builtin_amdgcn_mfma_f32_16x16x32_bf16(afr[pl][0], bfr[fc][0], acc[pl][fc], 0, 0, 0);
                acc[pl][fc] = __builtin_amdgcn_mfma_f32_16x16x32_bf16(afr[pl][1], bfr[fc][1], acc[pl][fc], 0, 0, 0);
            }
    }

    const int rg0 = lk8 * 4;
#pragma unroll
    for (int fr = 0; fr < 4; fr++) {
#pragma unroll
        for (int fc = 0; fc < 4; fc++) {
            int cn = n0 + wn * 64 + fc * 16 + lr;
            float bi = bias[e * D_DIM + cn];
            f32x4 v = acc[fr][fc];
#pragma unroll
            for (int rg = 0; rg < 4; rg++) {
                int rm = m0 + wm * 64 + fr * 16 + rg0 + rg;
                if (rm < ne) {
                    int s = base + rm;
                    int tok = perm[s];
                    unsafeAtomicAdd(&Out[(size_t)tok * D_DIM + cn], wgt[s] * (v[rg] + bi));
                }
            }
        }
    }
}

// ---------------- launch ----------------

extern "C" void kernel_launch(void* const* d_in, const int* in_sizes, int n_in,
                              void* d_out, int out_size, void* d_ws, size_t ws_size,
                              hipStream_t stream) {
    const float* x  = (const float*)d_in[0];
    const float* Wg = (const float*)d_in[1];
    const float* bg = (const float*)d_in[2];
    const float* W1 = (const float*)d_in[3];
    const float* b1 = (const float*)d_in[4];
    const float* W2 = (const float*)d_in[5];
    const float* b2 = (const float*)d_in[6];
    float* out = (float*)d_out;

    char* p = (char*)d_ws;
    ushort_t* xb  = (ushort_t*)p; p += (size_t)N_TOK * D_DIM * 2;
    ushort_t* W1T = (ushort_t*)p; p += (size_t)E_EXPERTS * H_DIM * D_DIM * 2;
    ushort_t* W2T = (ushort_t*)p; p += (size_t)E_EXPERTS * D_DIM * H_DIM * 2;
    ushort_t* Hb  = (ushort_t*)p; p += (size_t)SLOTS * H_DIM * 2;
    int*   top_idx = (int*)p;   p += (size_t)N_TOK * 2 * 4;
    float* top_w   = (float*)p; p += (size_t)N_TOK * 2 * 4;
    int*   perm    = (int*)p;   p += (size_t)SLOTS * 4;
    float* wgt     = (float*)p; p += (size_t)SLOTS * 4;
    int*   bc      = (int*)p;   p += SCAT_BLOCKS * E_EXPERTS * 4;
    int*   basep   = (int*)p;   p += SCAT_BLOCKS * E_EXPERTS * 4;
    int*   counts  = (int*)p;   p += 64;
    int*   offsets = (int*)p;   p += 64;

    hipMemsetAsync(d_out, 0, (size_t)out_size * sizeof(float), stream);

    gate_kernel<<<N_TOK / 4, 256, 0, stream>>>(x, Wg, bg, xb, top_idx, top_w);
    transpose_conv_kernel<<<dim3(H_DIM / 64, D_DIM / 64, E_EXPERTS), 256, 0, stream>>>(W1, W1T, D_DIM, H_DIM);
    transpose_conv_kernel<<<dim3(D_DIM / 64, H_DIM / 64, E_EXPERTS), 256, 0, stream>>>(W2, W2T, H_DIM, D_DIM);
    hist_kernel<<<SCAT_BLOCKS, 256, 0, stream>>>(top_idx, bc);
    scan_kernel<<<1, 64, 0, stream>>>(bc, counts, offsets, basep);
    scatter_kernel<<<SCAT_BLOCKS, 256, 0, stream>>>(top_idx, top_w, basep, perm, wgt);
    moe_gemm1_kernel<<<8 * 10 * (H_DIM / 128), 512, 0, stream>>>(
        xb, W1T, b1, offsets, counts, perm, Hb);
    moe_gemm2_kernel<<<8 * 20 * (D_DIM / 128), 256, 0, stream>>>(
        Hb, W2T, b2, offsets, counts, perm, wgt, out);
}

// Round 16
// 326.168 us; speedup vs baseline: 1.0418x; 1.0418x over previous
//
#include <hip/hip_runtime.h>
#include <hip/hip_bf16.h>
#include <math.h>

#define E_EXPERTS 8
#define D_DIM 768
#define H_DIM 3072
#define N_TOK 8192          // B*T = 4*2048
#define SLOTS (2 * N_TOK)
#define SCAT_BLOCKS 32      // hist/scatter blocks (256 tokens each)

typedef unsigned short ushort_t;
typedef __attribute__((ext_vector_type(8))) __bf16 bf16x8;
typedef __attribute__((ext_vector_type(4))) float f32x4;

__device__ __forceinline__ unsigned short f2bf(float f) {
    unsigned int u = __float_as_uint(f);
    unsigned int r = (u + 0x7FFFu + ((u >> 16) & 1u)) >> 16;
    return (unsigned short)r;
}

// async 16B global -> LDS (wave-uniform LDS base + lane*16; global addr per-lane)
__device__ __forceinline__ void gload_lds16(const void* g, void* l) {
    __builtin_amdgcn_global_load_lds(
        (const __attribute__((address_space(1))) unsigned int*)g,
        (__attribute__((address_space(3))) unsigned int*)l, 16, 0, 0);
}

// ---------------- prep kernels ----------------

// dst[e][c][r] = bf16(src[e][r][c]);  R,C multiples of 64
__global__ void transpose_conv_kernel(const float* __restrict__ src, ushort_t* __restrict__ dst,
                                      int R, int C) {
    __shared__ float tile[64][65];
    int e = blockIdx.z;
    const float* S = src + (size_t)e * R * C;
    ushort_t* Dp = dst + (size_t)e * R * C;
    int c0 = blockIdx.x * 64, r0 = blockIdx.y * 64;
    int tx = threadIdx.x & 15, ty = threadIdx.x >> 4;  // 16 x 16
#pragma unroll
    for (int p = 0; p < 4; p++) {
        float4 v = *(const float4*)&S[(size_t)(r0 + ty + 16 * p) * C + c0 + tx * 4];
        tile[ty + 16 * p][tx * 4 + 0] = v.x;
        tile[ty + 16 * p][tx * 4 + 1] = v.y;
        tile[ty + 16 * p][tx * 4 + 2] = v.z;
        tile[ty + 16 * p][tx * 4 + 3] = v.w;
    }
    __syncthreads();
#pragma unroll
    for (int p = 0; p < 4; p++) {
        int cc = ty + 16 * p;
        int rr = tx * 4;
        ushort4 o;
        o.x = f2bf(tile[rr + 0][cc]);
        o.y = f2bf(tile[rr + 1][cc]);
        o.z = f2bf(tile[rr + 2][cc]);
        o.w = f2bf(tile[rr + 3][cc]);
        *(ushort4*)&Dp[(size_t)(c0 + cc) * R + r0 + rr] = o;
    }
}

// ---------------- routing ----------------

__global__ void gate_kernel(const float* __restrict__ x, const float* __restrict__ Wg,
                            const float* __restrict__ bg, ushort_t* __restrict__ xb,
                            int* __restrict__ top_idx, float* __restrict__ top_w) {
    int w = threadIdx.x >> 6, lane = threadIdx.x & 63;
    int t = blockIdx.x * 4 + w;
    if (t >= N_TOK) return;
    const float* xr = x + (size_t)t * D_DIM;
    float xs[12];
#pragma unroll
    for (int j = 0; j < 12; j++) xs[j] = xr[lane + 64 * j];
#pragma unroll
    for (int j = 0; j < 12; j++) xb[(size_t)t * D_DIM + lane + 64 * j] = f2bf(xs[j]);
    float pr[8];
#pragma unroll
    for (int ee = 0; ee < 8; ee++) {
        const float* wr = Wg + ee * D_DIM;
        float p = 0.f;
#pragma unroll
        for (int j = 0; j < 12; j++) p += xs[j] * wr[lane + 64 * j];
#pragma unroll
        for (int o = 32; o > 0; o >>= 1) p += __shfl_xor(p, o);
        pr[ee] = p + bg[ee];
    }
    float mx = pr[0];
#pragma unroll
    for (int ee = 1; ee < 8; ee++) mx = fmaxf(mx, pr[ee]);
    float s = 0.f;
#pragma unroll
    for (int ee = 0; ee < 8; ee++) { pr[ee] = expf(pr[ee] - mx); s += pr[ee]; }
    float inv = 1.f / s;
#pragma unroll
    for (int ee = 0; ee < 8; ee++) pr[ee] *= inv;
    int i0 = 0;
#pragma unroll
    for (int ee = 1; ee < 8; ee++) if (pr[ee] > pr[i0]) i0 = ee;
    int i1 = -1;
#pragma unroll
    for (int ee = 0; ee < 8; ee++) {
        if (ee == i0) continue;
        if (i1 < 0 || pr[ee] > pr[i1]) i1 = ee;
    }
    if (lane == 0) {
        top_idx[2 * t] = i0;
        top_idx[2 * t + 1] = i1;
        top_w[2 * t] = pr[i0];
        top_w[2 * t + 1] = pr[i1];
    }
}

__global__ void hist_kernel(const int* __restrict__ top_idx, int* __restrict__ bc) {
    __shared__ int h[E_EXPERTS];
    if (threadIdx.x < E_EXPERTS) h[threadIdx.x] = 0;
    __syncthreads();
    int t = blockIdx.x * 256 + threadIdx.x;
    atomicAdd(&h[top_idx[2 * t]], 1);
    atomicAdd(&h[top_idx[2 * t + 1]], 1);
    __syncthreads();
    if (threadIdx.x < E_EXPERTS) bc[blockIdx.x * E_EXPERTS + threadIdx.x] = h[threadIdx.x];
}

__global__ void scan_kernel(const int* __restrict__ bc, int* __restrict__ counts,
                            int* __restrict__ offsets, int* __restrict__ base) {
    int tid = threadIdx.x;
    if (tid < E_EXPERTS) {
        int acc = 0;
        for (int b = 0; b < SCAT_BLOCKS; b++) {
            base[b * E_EXPERTS + tid] = acc;
            acc += bc[b * E_EXPERTS + tid];
        }
        counts[tid] = acc;
    }
    __syncthreads();
    if (tid == 0) {
        int acc = 0;
        for (int e = 0; e < E_EXPERTS; e++) { offsets[e] = acc; acc += counts[e]; }
    }
    __syncthreads();
    if (tid < E_EXPERTS) {
        int o = offsets[tid];
        for (int b = 0; b < SCAT_BLOCKS; b++) base[b * E_EXPERTS + tid] += o;
    }
}

__global__ void scatter_kernel(const int* __restrict__ top_idx, const float* __restrict__ top_w,
                               const int* __restrict__ base, int* __restrict__ perm,
                               float* __restrict__ wgt, int* __restrict__ tok2slot) {
    __shared__ int cur[E_EXPERTS];
    if (threadIdx.x < E_EXPERTS) cur[threadIdx.x] = 0;
    __syncthreads();
    int t = blockIdx.x * 256 + threadIdx.x;
#pragma unroll
    for (int sl = 0; sl < 2; sl++) {
        int ee = top_idx[2 * t + sl];
        int p = atomicAdd(&cur[ee], 1);
        int s = base[blockIdx.x * E_EXPERTS + ee] + p;
        perm[s] = t;
        wgt[s] = top_w[2 * t + sl];
        tok2slot[2 * t + sl] = s;
    }
}

// combine: out[t][d] = y[s0][d] + y[s1][d]  (nt on the stream-once accesses)
__global__ void combine_kernel(const float* __restrict__ y, const int* __restrict__ tok2slot,
                               float* __restrict__ out) {
    int idx = blockIdx.x * blockDim.x + threadIdx.x;
    int stride = gridDim.x * blockDim.x;
    const int QR = D_DIM / 4;  // float4 per row
    for (int i = idx; i < N_TOK * QR; i += stride) {
        int t = i / QR, d4 = i - t * QR;
        int s0 = tok2slot[2 * t], s1 = tok2slot[2 * t + 1];
        f32x4 a = __builtin_nontemporal_load((const f32x4*)(y + (size_t)s0 * D_DIM) + d4);
        f32x4 b = __builtin_nontemporal_load((const f32x4*)(y + (size_t)s1 * D_DIM) + d4);
        f32x4 o = a + b;
        __builtin_nontemporal_store(o, (f32x4*)(out + (size_t)t * D_DIM) + d4);
    }
}

// ------- GEMM1 (r13-proven): 256x128 tile, 512 threads (8 waves 4Mx2N), BK=64 -------
// Single-buffer 48 KiB LDS, __launch_bounds__(512,2), VGPR 64. K-tile in kk halves.
// Per K-tile: sync; {8 reads, 16 MFMA} x2; sync; stage t+1.
// Swizzle: source granule (tid&7)^(row&7), LDS dest linear; reads XOR granule with (lr&7).
__global__ __launch_bounds__(512, 2) void moe_gemm1_kernel(
    const ushort_t* __restrict__ A, const ushort_t* __restrict__ BT,
    const float* __restrict__ bias, const int* __restrict__ offsets,
    const int* __restrict__ counts, const int* __restrict__ perm,
    ushort_t* __restrict__ Hout) {
    constexpr int K = D_DIM;
    constexpr int KT = K / 64;
    constexpr int NB = H_DIM / 128;   // 24
    constexpr int MBL = 10;           // covers ne <= 2560

    const int wgid = blockIdx.x;
    const int c = wgid & 7;
    const int r = wgid >> 3;
    const int mb = r % MBL;
    const int q = r / MBL;
    const int g = q * 8 + c;
    const int e = g / NB;
    const int nb = g % NB;

    const int ne = counts[e];
    const int m0 = mb * 256;
    if (m0 >= ne) return;
    const int n0 = nb * 128;
    const int base = offsets[e];
    const ushort_t* Bt = BT + (size_t)e * ((size_t)H_DIM * K);

    __shared__ alignas(16) ushort_t As[256 * 64];   // 32 KB
    __shared__ alignas(16) ushort_t Bs[128 * 64];   // 16 KB

    const int tid = threadIdx.x;
    const int lane = tid & 63;
    const int w = tid >> 6;
    const int wm = w >> 1, wn = w & 1;           // 4 x 2 wave grid
    const int lr = lane & 15;
    const int lk8 = lane >> 4;

    const int trow = tid >> 3;                   // 0..63
    const int sg8 = (((tid & 7) ^ (trow & 7)) * 8);
    int a_off[4], b_off[2];
#pragma unroll
    for (int i = 0; i < 4; i++) {
        int row = i * 64 + trow;
        int rcl = min(m0 + row, ne - 1);
        a_off[i] = perm[base + rcl] * K + sg8;
    }
#pragma unroll
    for (int i = 0; i < 2; i++)
        b_off[i] = (n0 + i * 64 + trow) * K + sg8;

    auto stage = [&](int tt) {
#pragma unroll
        for (int i = 0; i < 4; i++)
            gload_lds16(A + (size_t)a_off[i] + (size_t)tt * 64, &As[(i * 512 + w * 64) * 8]);
#pragma unroll
        for (int i = 0; i < 2; i++)
            gload_lds16(Bt + (size_t)b_off[i] + (size_t)tt * 64, &Bs[(i * 512 + w * 64) * 8]);
    };

    f32x4 acc[4][4];
#pragma unroll
    for (int i = 0; i < 4; i++)
#pragma unroll
        for (int j = 0; j < 4; j++) acc[i][j] = (f32x4){0.f, 0.f, 0.f, 0.f};

    const int cg0 = ((0 * 4 + lk8) ^ (lr & 7)) << 3;
    const int cg1 = ((1 * 4 + lk8) ^ (lr & 7)) << 3;

    stage(0);
    for (int t = 0; t < KT; ++t) {
        __syncthreads();                         // vm-drain: tile t visible in LDS
        {
            bf16x8 bfr[4], afr[4];
#pragma unroll
            for (int f = 0; f < 4; f++)
                bfr[f] = *(const bf16x8*)&Bs[(wn * 64 + f * 16 + lr) * 64 + cg0];
#pragma unroll
            for (int f = 0; f < 4; f++)
                afr[f] = *(const bf16x8*)&As[(wm * 64 + f * 16 + lr) * 64 + cg0];
#pragma unroll
            for (int fm = 0; fm < 4; fm++)
#pragma unroll
                for (int fc = 0; fc < 4; fc++)
                    acc[fm][fc] = __builtin_amdgcn_mfma_f32_16x16x32_bf16(afr[fm], bfr[fc], acc[fm][fc], 0, 0, 0);
        }
        {
            bf16x8 bfr[4], afr[4];
#pragma unroll
            for (int f = 0; f < 4; f++)
                bfr[f] = *(const bf16x8*)&Bs[(wn * 64 + f * 16 + lr) * 64 + cg1];
#pragma unroll
            for (int f = 0; f < 4; f++)
                afr[f] = *(const bf16x8*)&As[(wm * 64 + f * 16 + lr) * 64 + cg1];
#pragma unroll
            for (int fm = 0; fm < 4; fm++)
#pragma unroll
                for (int fc = 0; fc < 4; fc++)
                    acc[fm][fc] = __builtin_amdgcn_mfma_f32_16x16x32_bf16(afr[fm], bfr[fc], acc[fm][fc], 0, 0, 0);
        }
        __syncthreads();                         // all waves done reading tile t
        if (t + 1 < KT) stage(t + 1);
    }

    const int rg0 = lk8 * 4;
#pragma unroll
    for (int fr = 0; fr < 4; fr++) {
#pragma unroll
        for (int fc = 0; fc < 4; fc++) {
            int cn = n0 + wn * 64 + fc * 16 + lr;
            float bi = bias[e * H_DIM + cn];
            f32x4 v = acc[fr][fc];
#pragma unroll
            for (int rg = 0; rg < 4; rg++) {
                int rm = m0 + wm * 64 + fr * 16 + rg0 + rg;
                if (rm < ne) {
                    float xv = v[rg] + bi;
                    // gelu(x) ~= x * sigmoid(2*0.7978845608*(x + 0.044715 x^3))
                    float u = xv * 1.5957691216f * __builtin_fmaf(0.044715f * xv, xv, 1.0f);
                    float gl = xv / (1.f + __expf(-u));
                    Hout[(size_t)(base + rm) * H_DIM + cn] = f2bf(gl);
                }
            }
        }
    }
}

// ------- GEMM2 (r11/r13-proven): 128x128, BK=64, 256 threads, single-buffer, (256,4) -------
// Per K-tile: sync; reads; sync; stage t+1 (async, overlaps MFMA); MFMA.
// A = Hb contiguous slots, B = W2T[e]; epilogue weighted+bias -> Y f32 (no atomics).
__global__ __launch_bounds__(256, 4) void moe_gemm2_kernel(
    const ushort_t* __restrict__ A, const ushort_t* __restrict__ BT,
    const float* __restrict__ bias, const int* __restrict__ offsets,
    const int* __restrict__ counts, const float* __restrict__ wgt,
    float* __restrict__ Y) {
    constexpr int K = H_DIM;
    constexpr int KT = K / 64;
    constexpr int NB = D_DIM / 128;   // 6
    constexpr int MBL = 20;           // covers ne <= 2560

    const int wgid = blockIdx.x;
    const int c = wgid & 7;
    const int r = wgid >> 3;
    const int mb = r % MBL;
    const int q = r / MBL;
    const int g = q * 8 + c;
    const int e = g / NB;
    const int nb = g % NB;

    const int ne = counts[e];
    const int m0 = mb * 128;
    if (m0 >= ne) return;
    const int n0 = nb * 128;
    const int base = offsets[e];
    const ushort_t* Bt = BT + (size_t)e * ((size_t)D_DIM * K);

    __shared__ alignas(16) ushort_t As[128 * 64];   // 16 KB
    __shared__ alignas(16) ushort_t Bs[128 * 64];   // 16 KB

    const int tid = threadIdx.x;
    const int lane = tid & 63;
    const int w = tid >> 6;
    const int wm = w >> 1, wn = w & 1;           // 2 x 2 wave grid
    const int lr = lane & 15;
    const int lk8 = lane >> 4;

    const int trow = tid >> 3;                   // 0..31
    const int sg8 = (((tid & 7) ^ (trow & 7)) * 8);
    int a_off[4], b_off[4];
#pragma unroll
    for (int i = 0; i < 4; i++) {
        int row = i * 32 + trow;
        int rcl = min(m0 + row, ne - 1);
        a_off[i] = (base + rcl) * K + sg8;
        b_off[i] = (n0 + row) * K + sg8;
    }

    auto stage = [&](int tt) {
#pragma unroll
        for (int i = 0; i < 4; i++)
            gload_lds16(A + (size_t)a_off[i] + (size_t)tt * 64, &As[(i * 256 + w * 64) * 8]);
#pragma unroll
        for (int i = 0; i < 4; i++)
            gload_lds16(Bt + (size_t)b_off[i] + (size_t)tt * 64, &Bs[(i * 256 + w * 64) * 8]);
    };

    f32x4 acc[4][4];
#pragma unroll
    for (int i = 0; i < 4; i++)
#pragma unroll
        for (int j = 0; j < 4; j++) acc[i][j] = (f32x4){0.f, 0.f, 0.f, 0.f};

    const int cg0 = ((0 * 4 + lk8) ^ (lr & 7)) << 3;
    const int cg1 = ((1 * 4 + lk8) ^ (lr & 7)) << 3;

    stage(0);
    for (int t = 0; t < KT; ++t) {
        __syncthreads();                         // vm-drain: tile t visible in LDS
        bf16x8 bfr[4][2], afr[4][2];
#pragma unroll
        for (int fc = 0; fc < 4; fc++) {
            int Rb = (wn * 64 + fc * 16 + lr) * 64;
            bfr[fc][0] = *(const bf16x8*)&Bs[Rb + cg0];
            bfr[fc][1] = *(const bf16x8*)&Bs[Rb + cg1];
        }
#pragma unroll
        for (int pl = 0; pl < 4; pl++) {
            int Ra = (wm * 64 + pl * 16 + lr) * 64;
            afr[pl][0] = *(const bf16x8*)&As[Ra + cg0];
            afr[pl][1] = *(const bf16x8*)&As[Ra + cg1];
        }
        __syncthreads();                         // lgkm-drain: reads in regs, buffer free
        if (t + 1 < KT) stage(t + 1);            // async loads overlap the MFMA below
#pragma unroll
        for (int pl = 0; pl < 4; pl++)
#pragma unroll
            for (int fc = 0; fc < 4; fc++) {
                acc[pl][fc] = __builtin_amdgcn_mfma_f32_16x16x32_bf16(afr[pl][0], bfr[fc][0], acc[pl][fc], 0, 0, 0);
                acc[pl][fc] = __builtin_amdgcn_mfma_f32_16x16x32_bf16(afr[pl][1], bfr[fc][1], acc[pl][fc], 0, 0, 0);
            }
    }

    const int rg0 = lk8 * 4;
#pragma unroll
    for (int fr = 0; fr < 4; fr++) {
#pragma unroll
        for (int fc = 0; fc < 4; fc++) {
            int cn = n0 + wn * 64 + fc * 16 + lr;
            float bi = bias[e * D_DIM + cn];
            f32x4 v = acc[fr][fc];
#pragma unroll
            for (int rg = 0; rg < 4; rg++) {
                int rm = m0 + wm * 64 + fr * 16 + rg0 + rg;
                if (rm < ne) {
                    int s = base + rm;
                    Y[(size_t)s * D_DIM + cn] = wgt[s] * (v[rg] + bi);
                }
            }
        }
    }
}

// ---------------- launch ----------------

extern "C" void kernel_launch(void* const* d_in, const int* in_sizes, int n_in,
                              void* d_out, int out_size, void* d_ws, size_t ws_size,
                              hipStream_t stream) {
    const float* x  = (const float*)d_in[0];
    const float* Wg = (const float*)d_in[1];
    const float* bg = (const float*)d_in[2];
    const float* W1 = (const float*)d_in[3];
    const float* b1 = (const float*)d_in[4];
    const float* W2 = (const float*)d_in[5];
    const float* b2 = (const float*)d_in[6];
    float* out = (float*)d_out;

    char* p = (char*)d_ws;
    ushort_t* xb  = (ushort_t*)p; p += (size_t)N_TOK * D_DIM * 2;
    ushort_t* W1T = (ushort_t*)p; p += (size_t)E_EXPERTS * H_DIM * D_DIM * 2;
    ushort_t* W2T = (ushort_t*)p; p += (size_t)E_EXPERTS * D_DIM * H_DIM * 2;
    ushort_t* Hb  = (ushort_t*)p; p += (size_t)SLOTS * H_DIM * 2;
    int*   top_idx = (int*)p;   p += (size_t)N_TOK * 2 * 4;
    float* top_w   = (float*)p; p += (size_t)N_TOK * 2 * 4;
    int*   perm    = (int*)p;   p += (size_t)SLOTS * 4;
    float* wgt     = (float*)p; p += (size_t)SLOTS * 4;
    int*   t2s     = (int*)p;   p += (size_t)SLOTS * 4;
    int*   bc      = (int*)p;   p += SCAT_BLOCKS * E_EXPERTS * 4;
    int*   basep   = (int*)p;   p += SCAT_BLOCKS * E_EXPERTS * 4;
    int*   counts  = (int*)p;   p += 64;
    int*   offsets = (int*)p;   p += 64;
    // y aliases xb+W1T (dead by GEMM2): 50.3 MB < 62.9 MB
    float* y = (float*)d_ws;

    gate_kernel<<<N_TOK / 4, 256, 0, stream>>>(x, Wg, bg, xb, top_idx, top_w);
    transpose_conv_kernel<<<dim3(H_DIM / 64, D_DIM / 64, E_EXPERTS), 256, 0, stream>>>(W1, W1T, D_DIM, H_DIM);
    transpose_conv_kernel<<<dim3(D_DIM / 64, H_DIM / 64, E_EXPERTS), 256, 0, stream>>>(W2, W2T, H_DIM, D_DIM);
    hist_kernel<<<SCAT_BLOCKS, 256, 0, stream>>>(top_idx, bc);
    scan_kernel<<<1, 64, 0, stream>>>(bc, counts, offsets, basep);
    scatter_kernel<<<SCAT_BLOCKS, 256, 0, stream>>>(top_idx, top_w, basep, perm, wgt, t2s);
    moe_gemm1_kernel<<<8 * 10 * (H_DIM / 128), 512, 0, stream>>>(
        xb, W1T, b1, offsets, counts, perm, Hb);
    moe_gemm2_kernel<<<8 * 20 * (D_DIM / 128), 256, 0, stream>>>(
        Hb, W2T, b2, offsets, counts, wgt, y);
    combine_kernel<<<2048, 256, 0, stream>>>(y, t2s, out);
}